// Round 15
// baseline (163.581 us; speedup 1.0000x reference)
//
#include <hip/hip_runtime.h>

#define GENE_N  200000
#define BATCH   200000
#define EMBED   128
#define BM      32
#define THREADS 512
#define LDS_STRIDE 136   // bf16 elems per LDS row: 128 + 8 pad
#define L2E     1.44269504088896340736f

typedef __attribute__((ext_vector_type(8))) short bf16x8;
typedef __attribute__((ext_vector_type(4))) float f32x4;

static __device__ __forceinline__ short f2bf(float f) {
    unsigned u = __builtin_bit_cast(unsigned, f);
    unsigned r = (u + 0x7fffu + ((u >> 16) & 1u)) >> 16;   // RNE
    return (short)(r & 0xffffu);
}
static __device__ __forceinline__ unsigned cvt_pk_bf16(float lo, float hi) {
    unsigned r;
    asm("v_cvt_pk_bf16_f32 %0, %1, %2" : "=v"(r) : "v"(lo), "v"(hi));
    return r;
}

// r15 = r14 with ONE change: uniform 10-tile blocks (gene 625, cell 1250;
// 1875 blocks = ~3.7 residency rounds).
// Why: r14 counters show waves ~90% idle yet no per-tile stall explains it;
// OccupancyPercent 37% < 50% cap points at slot idling — with exactly one
// residency round (512 blocks), a CU whose 36-tile block finishes early
// never refills. Fine uniform blocks let the dispatcher rebalance; tail
// shrinks from O(spread of 36-tile blocks) to O(10 tiles).
__global__ __launch_bounds__(THREADS, 4)
void hetagg_kernel(const float* __restrict__ gene_feat,
                   const float* __restrict__ cell_feat,
                   const float* __restrict__ gWf, const float* __restrict__ gbf,
                   const float* __restrict__ gWb, const float* __restrict__ gbb,
                   const float* __restrict__ cWf, const float* __restrict__ cbf,
                   const float* __restrict__ cWb, const float* __restrict__ cbb,
                   const int* __restrict__ c_ids, const int* __restrict__ p_ids,
                   const int* __restrict__ n_ids, float* __restrict__ out,
                   int gene_blocks, int cell_blocks)
{
    __shared__ short A_lds[2][BM * LDS_STRIDE];

    const int  bid     = blockIdx.x;
    const bool is_gene = (bid < gene_blocks);
    const int  tid     = threadIdx.x;
    const int  wid     = tid >> 6;
    const int  lane    = tid & 63;
    const int  lgrp    = lane >> 4;   // 0..3
    const int  lcol    = lane & 15;   // 0..15
    const int  dir     = wid >> 2;    // 0 fwd, 1 bwd
    const int  jt      = wid & 3;     // 16-wide j block
    const int  j       = jt * 16 + lcol;   // W-row index for fragments

    const float* feat = is_gene ? gene_feat : cell_feat;
    const float* W    = is_gene ? (dir ? gWb : gWf) : (dir ? cWb : cWf);
    const float* Bv   = is_gene ? (dir ? gbb : gbf) : (dir ? cbb : cbf);

    // exp2-domain gate scales folded into weights:
    //   a0 = -i*log2e (u=2^a0=e^-i); a1 = 2g*log2e (v=e^{2g}); a2 = -o*log2e (w=e^-o)
    const float gsc[3] = {-L2E, 2.0f * L2E, -L2E};

    // per-r biases: after the operand swap, acc reg r maps to
    // j_out = jt*16 + lgrp*4 + r (uniform in lcol).
    f32x4 binit0, binit1, binit2;
#pragma unroll
    for (int r = 0; r < 4; ++r) {
        const int jr = jt * 16 + lgrp * 4 + r;
        binit0[r] = -L2E * Bv[jr];
        binit1[r] = 2.0f * L2E * Bv[128 + jr];
        binit2[r] = -L2E * Bv[192 + jr];
    }

    // W fragments (A-operand after swap): lane holds W[jt*16+(lane&15)][k],
    // k = (lane>>4)*8 + s*32 + e
    bf16x8 bfrag[3][4];
    {
        const int gate_base[3] = {0, 128, 192};
#pragma unroll
        for (int q = 0; q < 3; ++q) {
            const float* wrow = W + (size_t)(gate_base[q] + j) * EMBED;
            const float  sc   = gsc[q];
#pragma unroll
            for (int s = 0; s < 4; ++s) {
                const int k0 = s * 32 + lgrp * 8;
                float4 w0 = *(const float4*)(wrow + k0);
                float4 w1 = *(const float4*)(wrow + k0 + 4);
                bf16x8 b;
                b[0] = f2bf(sc * w0.x); b[1] = f2bf(sc * w0.y);
                b[2] = f2bf(sc * w0.z); b[3] = f2bf(sc * w0.w);
                b[4] = f2bf(sc * w1.x); b[5] = f2bf(sc * w1.y);
                b[6] = f2bf(sc * w1.z); b[7] = f2bf(sc * w1.w);
                bfrag[q][s] = b;
            }
        }
    }

    const int myb    = is_gene ? bid : (bid - gene_blocks);
    const int nb     = is_gene ? gene_blocks : cell_blocks;
    const int ntiles = is_gene ? (BATCH / BM) : (2 * BATCH / BM);
    const int nk     = (ntiles - myb + nb - 1) / nb;   // == 10 uniformly

    const int r0 = tid >> 5;   // 0..15 (row within half-pass)
    const int cc = tid & 31;   // float4 col within row

#define FETCH_ID(grow) (is_gene ? c_ids[(grow)] \
                       : ((grow) < BATCH ? p_ids[(grow)] - GENE_N \
                                         : n_ids[(grow) - BATCH] - GENE_N))

    // ---- prologue: rows(0)->rvA, rows(1)->rvB, ids(2)->idO ----
    float4 rvA[2], rvB[2];
    int    idE[2], idO[2];
    {
        int id0[2], id1[2];
        const int ta = myb * BM;
#pragma unroll
        for (int p = 0; p < 2; ++p) id0[p] = FETCH_ID(ta + r0 + p * 16);
#pragma unroll
        for (int p = 0; p < 2; ++p)
            rvA[p] = ((const float4*)(feat + (size_t)id0[p] * EMBED))[cc];
        if (nk > 1) {
            const int tb = (myb + nb) * BM;
#pragma unroll
            for (int p = 0; p < 2; ++p) id1[p] = FETCH_ID(tb + r0 + p * 16);
#pragma unroll
            for (int p = 0; p < 2; ++p)
                rvB[p] = ((const float4*)(feat + (size_t)id1[p] * EMBED))[cc];
        }
        if (nk > 2) {
            const int tc = (myb + 2 * nb) * BM;
#pragma unroll
            for (int p = 0; p < 2; ++p) idO[p] = FETCH_ID(tc + r0 + p * 16);
        }
    }

    int pb = 0;   // LDS buffer parity

    // Tile body: [fetch ids(K+3) -> IDF, FIRST in FIFO] -> stage RV ->
    // drain+barrier -> refill RV=rows(K+2) via IDU -> MFMA + epilogue + nt store.
#define TILE_BODY(K, RV, IDF, IDU)                                             \
    {                                                                           \
        const int t_    = myb + (K) * nb;                                       \
        const int base_ = t_ * BM;                                              \
        short* buf = A_lds[pb];                                                 \
        if ((K) + 3 < nk) {                                                     \
            const int tn_ = (myb + ((K) + 3) * nb) * BM;                        \
            _Pragma("unroll")                                                   \
            for (int p = 0; p < 2; ++p) IDF[p] = FETCH_ID(tn_ + r0 + p * 16);   \
        }                                                                       \
        _Pragma("unroll")                                                       \
        for (int p = 0; p < 2; ++p) {                                           \
            int2 sv;                                                            \
            sv.x = (int)cvt_pk_bf16(RV[p].x, RV[p].y);                          \
            sv.y = (int)cvt_pk_bf16(RV[p].z, RV[p].w);                          \
            *(int2*)&buf[(r0 + p * 16) * LDS_STRIDE + cc * 4] = sv;             \
        }                                                                       \
        asm volatile("s_waitcnt lgkmcnt(0)" ::: "memory");                      \
        __builtin_amdgcn_s_barrier();                                           \
        if ((K) + 2 < nk) {                                                     \
            _Pragma("unroll")                                                   \
            for (int p = 0; p < 2; ++p)                                         \
                RV[p] = ((const float4*)(feat + (size_t)IDU[p] * EMBED))[cc];   \
        }                                                                       \
        _Pragma("unroll")                                                       \
        for (int mt = 0; mt < 2; ++mt) {                                        \
            f32x4 acc0 = binit0;                                                \
            f32x4 acc1 = binit1;                                                \
            f32x4 acc2 = binit2;                                                \
            const int m_ = mt * 16 + lcol;                                      \
            _Pragma("unroll")                                                   \
            for (int s = 0; s < 4; ++s) {                                       \
                bf16x8 a = *(const bf16x8*)&buf[m_ * LDS_STRIDE + s * 32 + lgrp * 8]; \
                acc0 = __builtin_amdgcn_mfma_f32_16x16x32_bf16(bfrag[0][s], a, acc0, 0, 0, 0); \
                acc1 = __builtin_amdgcn_mfma_f32_16x16x32_bf16(bfrag[1][s], a, acc1, 0, 0, 0); \
                acc2 = __builtin_amdgcn_mfma_f32_16x16x32_bf16(bfrag[2][s], a, acc2, 0, 0, 0); \
            }                                                                   \
            /* h = sigma(o)*tanh(sigma(i)*tanh(g)); c=N/D, Pade folded: */      \
            /* h = N(15D^2+N^2) * rcp(D(15D^2+6N^2)(1+w)); clamp a<=15  */      \
            f32x4 hv;                                                           \
            _Pragma("unroll")                                                   \
            for (int r = 0; r < 4; ++r) {                                       \
                const float a0 = fminf(acc0[r], 15.0f);                         \
                const float a1 = fminf(acc1[r], 15.0f);                         \
                const float a2 = fminf(acc2[r], 15.0f);                         \
                const float u  = __builtin_amdgcn_exp2f(a0);                    \
                const float v  = __builtin_amdgcn_exp2f(a1);                    \
                const float w  = __builtin_amdgcn_exp2f(a2);                    \
                const float N  = v - 1.0f;                                      \
                const float D  = (1.0f + u) * (v + 1.0f);                       \
                const float D2 = D * D;                                         \
                const float N2 = N * N;                                         \
                const float t1 = fmaf(15.0f, D2, N2);                           \
                const float t2 = fmaf(5.0f, N2, t1);                            \
                const float num = N * t1;                                       \
                const float den = D * t2 * (1.0f + w);                          \
                hv[r] = num * __builtin_amdgcn_rcpf(den);                       \
            }                                                                   \
            const int row = base_ + mt * 16 + lcol;                             \
            const size_t orow = (size_t)(is_gene ? row : (BATCH + row));        \
            __builtin_nontemporal_store(hv,                                     \
                (f32x4*)&out[orow * 128 + dir * 64 + jt * 16 + lgrp * 4]);      \
        }                                                                       \
        pb ^= 1;                                                                \
    }

    int k = 0;
    for (; k + 1 < nk; k += 2) {
        TILE_BODY(k, rvA, idE, idO);       // fetch ids(k+3)->idE, use idO
        TILE_BODY(k + 1, rvB, idO, idE);   // fetch ids(k+4)->idO, use idE
    }
    if (k < nk) TILE_BODY(k, rvA, idE, idO);

#undef TILE_BODY
#undef FETCH_ID
}

extern "C" void kernel_launch(void* const* d_in, const int* in_sizes, int n_in,
                              void* d_out, int out_size, void* d_ws, size_t ws_size,
                              hipStream_t stream)
{
    const float* gene_feat = (const float*)d_in[0];
    const float* cell_feat = (const float*)d_in[1];
    const float* gWf = (const float*)d_in[2];
    const float* gbf = (const float*)d_in[3];
    const float* gWb = (const float*)d_in[4];
    const float* gbb = (const float*)d_in[5];
    const float* cWf = (const float*)d_in[6];
    const float* cbf = (const float*)d_in[7];
    const float* cWb = (const float*)d_in[8];
    const float* cbb = (const float*)d_in[9];
    const int* c_ids = (const int*)d_in[10];
    const int* p_ids = (const int*)d_in[11];
    const int* n_ids = (const int*)d_in[12];
    float* out = (float*)d_out;

    const int gene_blocks = 625;    // 6250 tiles  -> exactly 10 tiles/block
    const int cell_blocks = 1250;   // 12500 tiles -> exactly 10 tiles/block
    dim3 grid(gene_blocks + cell_blocks);   // 1875 blocks, ~3.7 rounds
    dim3 block(THREADS);
    hipLaunchKernelGGL(hetagg_kernel, grid, block, 0, stream,
                       gene_feat, cell_feat, gWf, gbf, gWb, gbb,
                       cWf, cbf, cWb, cbb, c_ids, p_ids, n_ids, out,
                       gene_blocks, cell_blocks);
}

// Round 17
// 132.619 us; speedup vs baseline: 1.2335x; 1.2335x over previous
//
#include <hip/hip_runtime.h>

#define GENE_N  200000
#define BATCH   200000
#define EMBED   128
#define BM      32
#define THREADS 512
#define LDS_STRIDE 136   // bf16 elems per LDS row: 128 + 8 pad
#define L2E     1.44269504088896340736f

typedef __attribute__((ext_vector_type(8))) short bf16x8;
typedef __attribute__((ext_vector_type(4))) float f32x4;

static __device__ __forceinline__ short f2bf(float f) {
    unsigned u = __builtin_bit_cast(unsigned, f);
    unsigned r = (u + 0x7fffu + ((u >> 16) & 1u)) >> 16;   // RNE
    return (short)(r & 0xffffu);
}
static __device__ __forceinline__ unsigned cvt_pk_bf16(float lo, float hi) {
    unsigned r;
    asm("v_cvt_pk_bf16_f32 %0, %1, %2" : "=v"(r) : "v"(lo), "v"(hi));
    return r;
}
// Raw s_barrier has NO compiler fence semantics: pin memory ops to their
// side with a sched_barrier (rule #18 class fix for the r16 replay race).
static __device__ __forceinline__ void barrier_fenced() {
    __builtin_amdgcn_s_barrier();
    __builtin_amdgcn_sched_barrier(0);
}

// r17 = r16 with sched_barrier(0) after every s_barrier.
// r16's race: hipcc hoisted post-barrier ds_reads (Out_lds store-phase
// gather / A-fragment reads) above the raw s_barrier (no IR fence), so a
// wave could read LDS before other waves' writes landed — passed the first
// correctness check, diverged across graph replays. sched_barrier(0) is a
// compile-time fence, zero runtime cost.
__global__ __launch_bounds__(THREADS, 4)
void hetagg_kernel(const float* __restrict__ gene_feat,
                   const float* __restrict__ cell_feat,
                   const float* __restrict__ gWf, const float* __restrict__ gbf,
                   const float* __restrict__ gWb, const float* __restrict__ gbb,
                   const float* __restrict__ cWf, const float* __restrict__ cbf,
                   const float* __restrict__ cWb, const float* __restrict__ cbb,
                   const int* __restrict__ c_ids, const int* __restrict__ p_ids,
                   const int* __restrict__ n_ids, float* __restrict__ out,
                   int gene_blocks, int cell_blocks)
{
    __shared__ short A_lds[2][BM * LDS_STRIDE];
    __shared__ float Out_lds[BM * EMBED];   // 16 KB staged output tile

    const int  bid     = blockIdx.x;
    const bool is_gene = (bid < gene_blocks);
    const int  tid     = threadIdx.x;
    const int  wid     = tid >> 6;
    const int  lane    = tid & 63;
    const int  lgrp    = lane >> 4;   // 0..3
    const int  lcol    = lane & 15;   // 0..15
    const int  dir     = wid >> 2;    // 0 fwd, 1 bwd
    const int  jt      = wid & 3;     // 16-wide j block
    const int  j       = jt * 16 + lcol;   // W-row index for fragments

    const float* feat = is_gene ? gene_feat : cell_feat;
    const float* W    = is_gene ? (dir ? gWb : gWf) : (dir ? cWb : cWf);
    const float* Bv   = is_gene ? (dir ? gbb : gbf) : (dir ? cbb : cbf);

    // exp2-domain gate scales folded into weights:
    //   a0 = -i*log2e (u=2^a0=e^-i); a1 = 2g*log2e (v=e^{2g}); a2 = -o*log2e (w=e^-o)
    const float gsc[3] = {-L2E, 2.0f * L2E, -L2E};

    // per-r biases: acc reg r maps to j_out = jt*16 + lgrp*4 + r.
    f32x4 binit0, binit1, binit2;
#pragma unroll
    for (int r = 0; r < 4; ++r) {
        const int jr = jt * 16 + lgrp * 4 + r;
        binit0[r] = -L2E * Bv[jr];
        binit1[r] = 2.0f * L2E * Bv[128 + jr];
        binit2[r] = -L2E * Bv[192 + jr];
    }

    // W fragments (A-operand after swap)
    bf16x8 bfrag[3][4];
    {
        const int gate_base[3] = {0, 128, 192};
#pragma unroll
        for (int q = 0; q < 3; ++q) {
            const float* wrow = W + (size_t)(gate_base[q] + j) * EMBED;
            const float  sc   = gsc[q];
#pragma unroll
            for (int s = 0; s < 4; ++s) {
                const int k0 = s * 32 + lgrp * 8;
                float4 w0 = *(const float4*)(wrow + k0);
                float4 w1 = *(const float4*)(wrow + k0 + 4);
                bf16x8 b;
                b[0] = f2bf(sc * w0.x); b[1] = f2bf(sc * w0.y);
                b[2] = f2bf(sc * w0.z); b[3] = f2bf(sc * w0.w);
                b[4] = f2bf(sc * w1.x); b[5] = f2bf(sc * w1.y);
                b[6] = f2bf(sc * w1.z); b[7] = f2bf(sc * w1.w);
                bfrag[q][s] = b;
            }
        }
    }

    const int myb    = is_gene ? bid : (bid - gene_blocks);
    const int nb     = is_gene ? gene_blocks : cell_blocks;
    const int ntiles = is_gene ? (BATCH / BM) : (2 * BATCH / BM);
    const int nk     = (ntiles - myb + nb - 1) / nb;

    const int r0 = tid >> 5;   // 0..15 (staging row)
    const int cc = tid & 31;   // float4 col within row

    // out-staging: write side chunk ch = dir*16 + jt*4 + lgrp, phys = ch^(row&7)
    const int wch = dir * 16 + jt * 4 + lgrp;
    // read side: thread t -> row = t>>4, chunks oi and oi+16, phys = ch^(row&7)
    const int orow_l = tid >> 4;          // 0..31
    const int oi     = tid & 15;          // 0..15
    const int rsw    = orow_l & 7;

#define FETCH_ID(grow) (is_gene ? c_ids[(grow)] \
                       : ((grow) < BATCH ? p_ids[(grow)] - GENE_N \
                                         : n_ids[(grow) - BATCH] - GENE_N))

    // ---- prologue: rows(0)->rvA, rows(1)->rvB, ids(2)->idO ----
    float4 rvA[2], rvB[2];
    int    idE[2], idO[2];
    {
        int id0[2], id1[2];
        const int ta = myb * BM;
#pragma unroll
        for (int p = 0; p < 2; ++p) id0[p] = FETCH_ID(ta + r0 + p * 16);
#pragma unroll
        for (int p = 0; p < 2; ++p)
            rvA[p] = ((const float4*)(feat + (size_t)id0[p] * EMBED))[cc];
        if (nk > 1) {
            const int tb = (myb + nb) * BM;
#pragma unroll
            for (int p = 0; p < 2; ++p) id1[p] = FETCH_ID(tb + r0 + p * 16);
#pragma unroll
            for (int p = 0; p < 2; ++p)
                rvB[p] = ((const float4*)(feat + (size_t)id1[p] * EMBED))[cc];
        }
        if (nk > 2) {
            const int tc = (myb + 2 * nb) * BM;
#pragma unroll
            for (int p = 0; p < 2; ++p) idO[p] = FETCH_ID(tc + r0 + p * 16);
        }
    }

    int pb = 0;   // LDS buffer parity

    // Tile body: [ids(K+3) first in FIFO] -> stage RV -> drain+fenced barrier
    // -> refill RV=rows(K+2) -> MFMA + epilogue -> Out_lds -> drain+fenced
    // barrier -> linear full-line nt stores.
#define TILE_BODY(K, RV, IDF, IDU)                                             \
    {                                                                           \
        const int t_    = myb + (K) * nb;                                       \
        const int base_ = t_ * BM;                                              \
        short* buf = A_lds[pb];                                                 \
        if ((K) + 3 < nk) {                                                     \
            const int tn_ = (myb + ((K) + 3) * nb) * BM;                        \
            _Pragma("unroll")                                                   \
            for (int p = 0; p < 2; ++p) IDF[p] = FETCH_ID(tn_ + r0 + p * 16);   \
        }                                                                       \
        _Pragma("unroll")                                                       \
        for (int p = 0; p < 2; ++p) {                                           \
            int2 sv;                                                            \
            sv.x = (int)cvt_pk_bf16(RV[p].x, RV[p].y);                          \
            sv.y = (int)cvt_pk_bf16(RV[p].z, RV[p].w);                          \
            *(int2*)&buf[(r0 + p * 16) * LDS_STRIDE + cc * 4] = sv;             \
        }                                                                       \
        asm volatile("s_waitcnt lgkmcnt(0)" ::: "memory");                      \
        barrier_fenced();                                                       \
        if ((K) + 2 < nk) {                                                     \
            _Pragma("unroll")                                                   \
            for (int p = 0; p < 2; ++p)                                         \
                RV[p] = ((const float4*)(feat + (size_t)IDU[p] * EMBED))[cc];   \
        }                                                                       \
        _Pragma("unroll")                                                       \
        for (int mt = 0; mt < 2; ++mt) {                                        \
            f32x4 acc0 = binit0;                                                \
            f32x4 acc1 = binit1;                                                \
            f32x4 acc2 = binit2;                                                \
            const int m_ = mt * 16 + lcol;                                      \
            _Pragma("unroll")                                                   \
            for (int s = 0; s < 4; ++s) {                                       \
                bf16x8 a = *(const bf16x8*)&buf[m_ * LDS_STRIDE + s * 32 + lgrp * 8]; \
                acc0 = __builtin_amdgcn_mfma_f32_16x16x32_bf16(bfrag[0][s], a, acc0, 0, 0, 0); \
                acc1 = __builtin_amdgcn_mfma_f32_16x16x32_bf16(bfrag[1][s], a, acc1, 0, 0, 0); \
                acc2 = __builtin_amdgcn_mfma_f32_16x16x32_bf16(bfrag[2][s], a, acc2, 0, 0, 0); \
            }                                                                   \
            f32x4 hv;                                                           \
            _Pragma("unroll")                                                   \
            for (int r = 0; r < 4; ++r) {                                       \
                const float a0 = fminf(acc0[r], 15.0f);                         \
                const float a1 = fminf(acc1[r], 15.0f);                         \
                const float a2 = fminf(acc2[r], 15.0f);                         \
                const float u  = __builtin_amdgcn_exp2f(a0);                    \
                const float v  = __builtin_amdgcn_exp2f(a1);                    \
                const float w  = __builtin_amdgcn_exp2f(a2);                    \
                const float N  = v - 1.0f;                                      \
                const float D  = (1.0f + u) * (v + 1.0f);                       \
                const float D2 = D * D;                                         \
                const float N2 = N * N;                                         \
                const float t1 = fmaf(15.0f, D2, N2);                           \
                const float t2 = fmaf(5.0f, N2, t1);                            \
                const float num = N * t1;                                       \
                const float den = D * t2 * (1.0f + w);                          \
                hv[r] = num * __builtin_amdgcn_rcpf(den);                       \
            }                                                                   \
            const int orw = mt * 16 + lcol;                                     \
            *(f32x4*)&Out_lds[orw * EMBED + ((wch ^ (orw & 7)) << 2)] = hv;     \
        }                                                                       \
        asm volatile("s_waitcnt lgkmcnt(0)" ::: "memory");                      \
        barrier_fenced();                                                       \
        /* linear streamed store: thread t -> row t>>4, chunks oi, oi+16 */     \
        {                                                                       \
            f32x4 o0 = *(const f32x4*)&Out_lds[orow_l * EMBED + ((oi ^ rsw) << 2)];        \
            f32x4 o1 = *(const f32x4*)&Out_lds[orow_l * EMBED + (((oi + 16) ^ rsw) << 2)]; \
            const int grow = base_ + orow_l;                                    \
            const size_t og = (size_t)(is_gene ? grow : (BATCH + grow)) * 128;  \
            __builtin_nontemporal_store(o0, (f32x4*)&out[og + oi * 4]);         \
            __builtin_nontemporal_store(o1, (f32x4*)&out[og + (oi + 16) * 4]);  \
        }                                                                       \
        pb ^= 1;                                                                \
    }

    int k = 0;
    for (; k + 1 < nk; k += 2) {
        TILE_BODY(k, rvA, idE, idO);       // fetch ids(k+3)->idE, use idO
        TILE_BODY(k + 1, rvB, idO, idE);   // fetch ids(k+4)->idO, use idE
    }
    if (k < nk) TILE_BODY(k, rvA, idE, idO);

#undef TILE_BODY
#undef FETCH_ID
}

extern "C" void kernel_launch(void* const* d_in, const int* in_sizes, int n_in,
                              void* d_out, int out_size, void* d_ws, size_t ws_size,
                              hipStream_t stream)
{
    const float* gene_feat = (const float*)d_in[0];
    const float* cell_feat = (const float*)d_in[1];
    const float* gWf = (const float*)d_in[2];
    const float* gbf = (const float*)d_in[3];
    const float* gWb = (const float*)d_in[4];
    const float* gbb = (const float*)d_in[5];
    const float* cWf = (const float*)d_in[6];
    const float* cbf = (const float*)d_in[7];
    const float* cWb = (const float*)d_in[8];
    const float* cbb = (const float*)d_in[9];
    const int* c_ids = (const int*)d_in[10];
    const int* p_ids = (const int*)d_in[11];
    const int* n_ids = (const int*)d_in[12];
    float* out = (float*)d_out;

    const int gene_blocks = 171;   // 6250 tiles of 32 rows -> 36-37 tiles/block
    const int cell_blocks = 341;   // 12500 tiles           -> 36-37 tiles/block
    dim3 grid(gene_blocks + cell_blocks);   // 512 = 2 blocks/CU, one round
    dim3 block(THREADS);
    hipLaunchKernelGGL(hetagg_kernel, grid, block, 0, stream,
                       gene_feat, cell_feat, gWf, gbf, gWb, gbb,
                       cWf, cbf, cWb, cbb, c_ids, p_ids, n_ids, out,
                       gene_blocks, cell_blocks);
}